// Round 2
// baseline (1286.878 us; speedup 1.0000x reference)
//
#include <hip/hip_runtime.h>
#include <stdint.h>

#define BB 8
#define RR 2048
#define CC 4096
#define KFRONT 1228   // int(4096*0.30)
#define KRAND  409    // int(4096*0.10)
#define NT 256
#define EPT 16        // CC / NT
#define ROWS 32       // input rows per block (= 64-wide u-stripe)
#define PAD 129

// ---------------- threefry2x32 (JAX), key=(0,42), ctr=(0,i) ----------------
// JAX partitionable 32-bit random_bits: bits = out0 ^ out1.
__device__ __forceinline__ uint32_t rotl32(uint32_t x, uint32_t r) {
  return (x << r) | (x >> (32u - r));
}

__device__ __forceinline__ uint32_t threefry_bits(uint32_t i) {
  const uint32_t ks0 = 0u, ks1 = 42u;
  const uint32_t ks2 = 0x1BD11BDAu ^ ks0 ^ ks1;
  uint32_t x0 = ks0;        // ctr_hi (=0) + ks0
  uint32_t x1 = i + ks1;    // ctr_lo + ks1
#define R4(a, b, c, d)                         \
  x0 += x1; x1 = rotl32(x1, (a)); x1 ^= x0;    \
  x0 += x1; x1 = rotl32(x1, (b)); x1 ^= x0;    \
  x0 += x1; x1 = rotl32(x1, (c)); x1 ^= x0;    \
  x0 += x1; x1 = rotl32(x1, (d)); x1 ^= x0;
  R4(13u, 15u, 26u, 6u)  x0 += ks1; x1 += ks2 + 1u;
  R4(17u, 29u, 16u, 24u) x0 += ks2; x1 += ks0 + 2u;
  R4(13u, 15u, 26u, 6u)  x0 += ks0; x1 += ks1 + 3u;
  R4(17u, 29u, 16u, 24u) x0 += ks1; x1 += ks2 + 4u;
  R4(13u, 15u, 26u, 6u)  x0 += ks2; x1 += ks0 + 5u;
#undef R4
  return x0 ^ x1;
}

// ---------------- shared state for radix select ----------------------------
struct SelSh {
  uint32_t hist4[4 * 256];  // per-wave histograms (contention /4)
  uint32_t cum[256];        // inclusive prefix over merged bins
  int sel_digit;
  int sel_below;
};

// k-th smallest (1-indexed) of the 4096 distinct composites
// ((u64)keys[j] << 12) | (j*NT + tid). MSB-first, 8-bit digits, NPASS passes.
template <int NPASS>
__device__ uint64_t radix_select(const uint32_t (&keys)[EPT], int tid, int k,
                                 SelSh* sh) {
  uint64_t prefix = 0;
  int kk = k;
  const int wave = tid >> 6;
  for (int p = NPASS - 1; p >= 0; --p) {
    const int shift = 8 * p;
    ((uint4*)sh->hist4)[tid] = make_uint4(0, 0, 0, 0);
    __syncthreads();
#pragma unroll
    for (int j = 0; j < EPT; ++j) {
      uint64_t comp = ((uint64_t)keys[j] << 12) | (uint32_t)(j * NT + tid);
      if ((comp >> (shift + 8)) == prefix)
        atomicAdd(&sh->hist4[wave * 256 + ((uint32_t)(comp >> shift) & 255u)],
                  1u);
    }
    __syncthreads();
    if (tid < 64) {
      uint4 h0 = ((const uint4*)(sh->hist4 + 0))[tid];
      uint4 h1 = ((const uint4*)(sh->hist4 + 256))[tid];
      uint4 h2 = ((const uint4*)(sh->hist4 + 512))[tid];
      uint4 h3 = ((const uint4*)(sh->hist4 + 768))[tid];
      uint32_t s0 = h0.x + h1.x + h2.x + h3.x;
      uint32_t s1 = h0.y + h1.y + h2.y + h3.y;
      uint32_t s2 = h0.z + h1.z + h2.z + h3.z;
      uint32_t s3 = h0.w + h1.w + h2.w + h3.w;
      uint32_t sum = s0 + s1 + s2 + s3;
      uint32_t inc = sum;
      for (int off = 1; off < 64; off <<= 1) {
        uint32_t v = __shfl_up(inc, (unsigned)off);
        if (tid >= off) inc += v;
      }
      uint32_t base = inc - sum;
      ((uint4*)sh->cum)[tid] =
          make_uint4(base + s0, base + s0 + s1, base + s0 + s1 + s2, base + sum);
    }
    __syncthreads();
    int cum = (int)sh->cum[tid];
    int prev = tid ? (int)sh->cum[tid - 1] : 0;
    if (cum >= kk && prev < kk) { sh->sel_digit = tid; sh->sel_below = prev; }
    __syncthreads();
    prefix = (prefix << 8) | (uint32_t)sh->sel_digit;
    kk -= sh->sel_below;
    __syncthreads();
  }
  return prefix;  // composite value of the k-th smallest
}

// ---------------- fused: select + mask-build + transpose + emit ------------
// out[b, v, u] = M[b, u>>1, ((u&1)<<11) + v]; block owns u in [u0,u0+64),
// i.e. input rows [u0/2, u0/2+32), all v. No global workspace used.
__global__ __launch_bounds__(NT) void fused_kernel(
    const float* __restrict__ score, float* __restrict__ outS,
    float* __restrict__ outT) {
  __shared__ SelSh sh;
  __shared__ uint32_t zbits[ROWS][PAD];  // student zero-mask bits, per row
  __shared__ uint32_t fbits[ROWS][PAD];  // front-set bits (teacher row 0)
  __shared__ float tin[ROWS][PAD];       // phase-2 transpose tile

  const int tid = threadIdx.x;
  const int stripe = blockIdx.x;  // 0..63
  const int b = blockIdx.y;       // 0..7
  const int u0 = stripe * 64;
  const int r0 = u0 >> 1;

  // ================= Phase 1: per-row exact selection ================
  for (int rr = 0; rr < ROWS; ++rr) {
    const int rowid = b * RR + (r0 + rr);
    const float* srow = score + (size_t)rowid * CC;
    uint32_t keyS[EPT], keyR[EPT];
#pragma unroll
    for (int j = 0; j < EPT; ++j) {
      int c = j * NT + tid;
      uint32_t fb = __float_as_uint(srow[c]);
      // IEEE total-order flip: ascending uint == ascending float
      keyS[j] = fb ^ ((uint32_t)((int32_t)fb >> 31) | 0x80000000u);
      // uniform order key: top 23 bits of random bits (stable ties by index)
      keyR[j] = threefry_bits((uint32_t)rowid * (uint32_t)CC + (uint32_t)c) >> 9;
    }
    uint64_t pivF = radix_select<6>(keyS, tid, KFRONT, &sh);  // 44-bit comp
    uint64_t pivR = radix_select<5>(keyR, tid, KRAND, &sh);   // 35-bit comp
#pragma unroll
    for (int j = 0; j < EPT; ++j) {
      int c = j * NT + tid;
      uint64_t compS = ((uint64_t)keyS[j] << 12) | (uint32_t)c;
      uint64_t compR = ((uint64_t)keyR[j] << 12) | (uint32_t)c;
      int isF = (compS <= pivF) ? 1 : 0;
      int isZ = (isF || (compR <= pivR)) ? 1 : 0;
      uint64_t bZ = __ballot(isZ);
      uint64_t bF = __ballot(isF);
      if ((tid & 31) == 0) {
        uint32_t wz = (tid & 32) ? (uint32_t)(bZ >> 32) : (uint32_t)bZ;
        uint32_t wf = (tid & 32) ? (uint32_t)(bF >> 32) : (uint32_t)bF;
        zbits[rr][c >> 5] = wz;
        fbits[rr][c >> 5] = wf;
      }
    }
  }
  __syncthreads();

  // ================= Phase 2: tiled transpose + masked emit ==========
  const int u_local = tid & 63;
  const int rl = u_local >> 1;
  const int half = u_local & 1;
  const bool isrow0 = (r0 + rl) == 0;  // teacher bug: only global row 0 masked
  float* oS = outS + (size_t)b * RR * CC + (size_t)(u0 + u_local);
  float* oT = outT + (size_t)b * RR * CC + (size_t)(u0 + u_local);

  for (int vt = 0; vt < 32; ++vt) {
    const int v0 = vt * 64;
    // stage 32 rows x 128 cols (two 64-wide halves), coalesced 256B runs
#pragma unroll
    for (int it = 0; it < 16; ++it) {
      int idx = it * NT + tid;
      int lrl = idx >> 7;
      int colsel = (idx >> 6) & 1;
      int lane = idx & 63;
      tin[lrl][colsel * 64 + lane] =
          score[(size_t)(b * RR + r0 + lrl) * CC + colsel * 2048 + v0 + lane];
    }
    __syncthreads();
    const int w0 = half * 64 + (v0 >> 5);
    const uint32_t z0 = zbits[rl][w0], z1 = zbits[rl][w0 + 1];
    const uint32_t f0 = fbits[rl][w0], f1 = fbits[rl][w0 + 1];
#pragma unroll
    for (int it = 0; it < 16; ++it) {
      int vl = it * 4 + (tid >> 6);  // 0..63
      float s = tin[rl][half * 64 + vl];
      uint32_t zw = (vl & 32) ? z1 : z0;
      uint32_t fw = (vl & 32) ? f1 : f0;
      int bit = vl & 31;
      float st = ((zw >> bit) & 1u) ? 0.0f : s;
      float te = isrow0 ? ((((fw >> bit) & 1u)) ? s : 0.0f) : s;
      size_t o = (size_t)(v0 + vl) * CC;
      oS[o] = st;
      oT[o] = te;
    }
    __syncthreads();  // tin reused next iteration
  }
}

extern "C" void kernel_launch(void* const* d_in, const int* in_sizes, int n_in,
                              void* d_out, int out_size, void* d_ws,
                              size_t ws_size, hipStream_t stream) {
  const float* score = (const float*)d_in[0];
  float* outS = (float*)d_out;
  float* outT = outS + (size_t)BB * RR * CC;
  dim3 grid(RR / ROWS, BB);  // 64 x 8
  hipLaunchKernelGGL(fused_kernel, grid, dim3(NT), 0, stream, score, outS,
                     outT);
}